// Round 12
// baseline (380.371 us; speedup 1.0000x reference)
//
#include <hip/hip_runtime.h>

// Problem constants (match reference)
#define D    128      // embedding dim
#define VSZ  200000   // vocab (emb has VSZ+1 rows, last row = 0)
#define NB   4096     // batch B
#define MM   50       // neighbors
#define DM   256      // 2*D
#define HSZ  512      // H
#define G4   2048     // 4*H
#define PROJ_BLKS 768 // proj grid-stride (blocks < PROJ_BLKS do proj work)

typedef __attribute__((ext_vector_type(8))) short short8;   // 8 bf16 = 4 VGPRs
typedef __attribute__((ext_vector_type(4))) float floatx4;  // MFMA acc

__device__ __forceinline__ float sigf(float x) { return 1.0f / (1.0f + __expf(-x)); }
__device__ __forceinline__ float tanhfast(float x) { return 1.0f - 2.0f / (__expf(2.0f * x) + 1.0f); }
__device__ __forceinline__ unsigned short f2bf(float x) {
    unsigned int u = __float_as_uint(x);
    u += 0x7FFFu + ((u >> 16) & 1u);   // round-to-nearest-even
    return (unsigned short)(u >> 16);
}
__device__ __forceinline__ float bf2f(unsigned short s) {
    return __uint_as_float(((unsigned int)s) << 16);
}

// async 16B global->LDS DMA (gfx950).  lds dest must be wave-uniform;
// HW writes dest + lane*16.  size must be a literal (4/12/16).
__device__ __forceinline__ void async_copy16(void* lds, const void* gsrc) {
    __builtin_amdgcn_global_load_lds(
        (const __attribute__((address_space(1))) unsigned int*)gsrc,
        (__attribute__((address_space(3))) unsigned int*)lds, 16, 0, 0);
}

// ---------------------------------------------------------------------------
// Kernel 1 (round-17, absorbs old k_pack): P = emb @ Wcat^T via bf16 MFMA.
// Blocks < PROJ_BLKS: software-pipelined grid-stride proj loop (verified R7;
// duty-cycle fix).  B-fragments now converted DIRECTLY from fp32 gcn_W in
// the prologue (identical f2bf values as the old Wb path -> identical MFMA
// inputs; kills the k_pack->k_proj dependency).  Blocks >= PROJ_BLKS (520
// blocks): pack Wihp/Whhp (fragment-linear bf16) + gb = bih+bhh for k_lstm;
// they exit before any barrier.  Rationale: 7 sequential launches cost
// ~15-20us each in inter-kernel gaps (dispatch sum ~215us vs 349us wall);
// kernel count 7 -> 4 is the cheapest remaining lever.
// ---------------------------------------------------------------------------
__global__ __launch_bounds__(256, 3) void k_proj_mfma(
    const float* __restrict__ emb, const float* __restrict__ gcn_W,
    const float* __restrict__ Wih, const float* __restrict__ Whh,
    const float* __restrict__ bih, const float* __restrict__ bhh,
    const float* __restrict__ gcn_lb, const float* __restrict__ gcn_b,
    unsigned short* __restrict__ P1, unsigned short* __restrict__ P2,
    unsigned short* __restrict__ Wihp, unsigned short* __restrict__ Whhp,
    float* __restrict__ gb, int nrows)
{
    __shared__ __align__(16) unsigned char Buf[2][16384];   // fp32 A, swizzled
    __shared__ unsigned short C[32 * 264];                  // 16896 B
    int t = threadIdx.x;

    if (blockIdx.x >= PROJ_BLKS) {
        // ---- pack blocks (old k_pack minus Wb): 520 * 256 = 133120 thr ----
        int pidx = (blockIdx.x - PROJ_BLKS) * 256 + t;
        if (pidx < 131072) {
            int ci = pidx & 65535;
            int lane = ci & 63, rest = ci >> 6;
            int ks = rest & 7, tile = rest >> 3;
            int n = tile * 16 + (lane & 15), k = ks * 32 + (lane >> 4) * 8;
            const float* src = (pidx < 65536) ? (Wih + (size_t)n * 256 + k)
                                              : (Whh + (size_t)n * 512 + k);
            unsigned short* dst = (pidx < 65536) ? Wihp : Whhp;
            short8 o;
            #pragma unroll
            for (int j = 0; j < 8; ++j) o[j] = (short)f2bf(src[j]);
            *(short8*)(dst + (size_t)ci * 8) = o;
        } else {
            int i = pidx - 131072;                 // < 2048 exactly
            gb[i] = bih[i] + bhh[i];
        }
        return;
    }

    int lane = t & 63, w = t >> 6;
    int nl = lane & 15, quad = lane >> 4;
    int n0 = w * 64;
    int ntile = (nrows + 31) >> 5;

    auto STAGE = [&](int pb, int tile) {
        int v0 = tile * 32;
        #pragma unroll
        for (int it = 0; it < 4; ++it) {
            int chunk = w * 4 + it;                // 16 chunks of 1KB
            int o = chunk * 1024 + lane * 16;      // linear LDS byte
            int row = o >> 9;
            int b = o & 511;
            int bs = b ^ ((row & 7) << 5);         // inverse swizzle on source
            int v = v0 + row;
            v = (v < nrows) ? v : (nrows - 1);     // clamp tail (stores guarded)
            async_copy16(Buf[pb] + chunk * 1024,
                         (const char*)emb + (size_t)v * 512 + bs);
        }
    };

    // B fragments converted once from fp32 gcn_W (same values as old Wb):
    // Wb[n][k] = f2bf(n<128 ? gcn_W[n*256+k] : gcn_W[(n-128)*256+128+k])
    short8 bfr[4][4];
    #pragma unroll
    for (int nt = 0; nt < 4; ++nt) {
        int n = n0 + nt * 16 + nl;
        const float* src = (n < 128) ? (gcn_W + (size_t)n * 256)
                                     : (gcn_W + (size_t)(n - 128) * 256 + 128);
        #pragma unroll
        for (int ks = 0; ks < 4; ++ks) {
            int k = ks * 32 + quad * 8;
            float4 lo = *(const float4*)(src + k);
            float4 hi = *(const float4*)(src + k + 4);
            short8 a;
            a[0] = (short)f2bf(lo.x); a[1] = (short)f2bf(lo.y);
            a[2] = (short)f2bf(lo.z); a[3] = (short)f2bf(lo.w);
            a[4] = (short)f2bf(hi.x); a[5] = (short)f2bf(hi.y);
            a[6] = (short)f2bf(hi.z); a[7] = (short)f2bf(hi.w);
            bfr[nt][ks] = a;
        }
    }

    STAGE(0, blockIdx.x);                          // prologue
    int pb = 0;
    bool first = true;
    for (int tile = blockIdx.x; tile < ntile; tile += PROJ_BLKS) {
        int nxt = tile + PROJ_BLKS;
        bool pf = (nxt < ntile);
        if (pf) STAGE(pb ^ 1, nxt);
        // counted wait: newest (4 prefetch [+4 stores after iter 0]) may stay
        // outstanding; everything older (current buffer's DMA) must be done.
        if (first) {
            if (pf) asm volatile("s_waitcnt vmcnt(4)" ::: "memory");
            else    asm volatile("s_waitcnt vmcnt(0)" ::: "memory");
        } else {
            if (pf) asm volatile("s_waitcnt vmcnt(8)" ::: "memory");
            else    asm volatile("s_waitcnt vmcnt(4)" ::: "memory");
        }
        __builtin_amdgcn_sched_barrier(0);
        __builtin_amdgcn_s_barrier();
        __builtin_amdgcn_sched_barrier(0);

        // ---- compute 32-row tile from Buf[pb] ----
        floatx4 acc[2][4];
        #pragma unroll
        for (int mt = 0; mt < 2; ++mt)
            #pragma unroll
            for (int nt = 0; nt < 4; ++nt)
                acc[mt][nt] = (floatx4){0.f, 0.f, 0.f, 0.f};
        const char* Sb = (const char*)Buf[pb];
        #pragma unroll
        for (int ks = 0; ks < 4; ++ks) {
            short8 af[2];
            #pragma unroll
            for (int mt = 0; mt < 2; ++mt) {
                int row = mt * 16 + nl;
                int b = ks * 128 + quad * 32;
                int ba = row * 512 + (b ^ ((row & 7) << 5));   // swizzled read
                float4 lo = *(const float4*)(Sb + ba);
                float4 hi = *(const float4*)(Sb + ba + 16);
                short8 a;
                a[0] = (short)f2bf(lo.x); a[1] = (short)f2bf(lo.y);
                a[2] = (short)f2bf(lo.z); a[3] = (short)f2bf(lo.w);
                a[4] = (short)f2bf(hi.x); a[5] = (short)f2bf(hi.y);
                a[6] = (short)f2bf(hi.z); a[7] = (short)f2bf(hi.w);
                af[mt] = a;
            }
            #pragma unroll
            for (int mt = 0; mt < 2; ++mt)
                #pragma unroll
                for (int nt = 0; nt < 4; ++nt)
                    acc[mt][nt] = __builtin_amdgcn_mfma_f32_16x16x32_bf16(
                        af[mt], bfr[nt][ks], acc[mt][nt], 0, 0, 0);
        }

        // ---- C-stage (bf16) ----
        #pragma unroll
        for (int nt = 0; nt < 4; ++nt) {
            int col = n0 + nt * 16 + nl;
            float bias = (col < 128) ? (gcn_lb[col] + gcn_b[col]) : 0.f;
            #pragma unroll
            for (int mt = 0; mt < 2; ++mt)
                #pragma unroll
                for (int reg = 0; reg < 4; ++reg)
                    C[(mt * 16 + quad * 4 + reg) * 264 + col] =
                        f2bf(acc[mt][nt][reg] + bias);
        }
        // lgkm-only barrier: C visible + Buf[pb] reads retired, WITHOUT
        // draining the in-flight prefetch (no vmcnt here).
        asm volatile("s_waitcnt lgkmcnt(0)" ::: "memory");
        __builtin_amdgcn_sched_barrier(0);
        __builtin_amdgcn_s_barrier();
        __builtin_amdgcn_sched_barrier(0);

        // ---- coalesced stores: 1024 16B chunks ----
        #pragma unroll
        for (int it = 0; it < 4; ++it) {
            int c = t + 256 * it;
            int row = c >> 5, c8 = c & 31;
            int v = tile * 32 + row;
            if (v < nrows) {
                int4 val = *(const int4*)(C + row * 264 + c8 * 8);
                unsigned short* dst = (c8 < 16) ? (P1 + (size_t)v * D + c8 * 8)
                                                : (P2 + (size_t)v * D + (c8 - 16) * 8);
                *(int4*)dst = val;
            }
        }
        pb ^= 1;
        first = false;
    }
}

// ---------------------------------------------------------------------------
// Kernel 2: neighbor aggregation.  ASM-forced gather pipeline (R11: 68us,
// identical to R9 -> random-gather service floor confirmed per pre-commit;
// algorithm frozen).
// ---------------------------------------------------------------------------
__global__ __launch_bounds__(256, 4) void k_nbr(
    const int* __restrict__ query, const int* __restrict__ support,
    const int* __restrict__ q_l1, const int* __restrict__ q_l2,
    const int* __restrict__ q_r1, const int* __restrict__ q_r2,
    const int* __restrict__ s_l1, const int* __restrict__ s_l2,
    const int* __restrict__ s_r1, const int* __restrict__ s_r2,
    const unsigned short* __restrict__ P1, const unsigned short* __restrict__ P2,
    const float* __restrict__ emb,
    const float* __restrict__ attn_W, const float* __restrict__ attn_b,
    const float* __restrict__ gate_W, const float* __restrict__ gate_lb,
    const float* __restrict__ gate_b,
    float* __restrict__ qv, unsigned short* __restrict__ qvbf,
    float* __restrict__ sv)
{
    __shared__ unsigned short proj[2 * MM * 136];   // bf16, 27.2 KB
    __shared__ float scw[2 * 64];
    __shared__ float scp[2][2][64];
    __shared__ float aw[D], gw[D];
    __shared__ float redg[4];
    __shared__ float gateS[2];
    __shared__ float oth[D];

    int bid = blockIdx.x;
    int item = bid >> 1;
    int side = bid & 1;
    int t = threadIdx.x;

    const int* cA; const int* cB; int selfid; float* outp; bool isq;
    if (item < NB) {
        isq = true;
        cA = (side ? q_r1 : q_l1) + (size_t)item * MM * 2;
        cB = (side ? q_r2 : q_l2) + (size_t)item * MM * 2;
        selfid = query[item * 2 + side];
        outp = qv + (size_t)item * DM + side * D;
    } else {
        isq = false;
        int i2 = item - NB;
        cA = (side ? s_r1 : s_l1) + (size_t)i2 * MM * 2;
        cB = (side ? s_r2 : s_l2) + (size_t)i2 * MM * 2;
        selfid = support[i2 * 2 + side];
        outp = sv + (size_t)i2 * DM + side * D;
    }
    if (t < D) { aw[t] = attn_W[t]; gw[t] = gate_W[t]; }

    // ---- 7 idx loads, asm-forced in flight together ----
    int2 idx[7];
    #pragma unroll
    for (int it = 0; it < 7; ++it) {
        int e8 = t + it * 256;
        int e8c = (e8 < 1600) ? e8 : 1599;
        int m = e8c >> 4;
        unsigned long long ca = (unsigned long long)
            ((m < MM) ? (cA + 2 * m) : (cB + 2 * (m - MM)));
        asm volatile("global_load_dwordx2 %0, %1, off"
                     : "=&v"(idx[it]) : "v"(ca));
    }
    asm volatile("s_waitcnt vmcnt(0)" ::: "memory");
    __builtin_amdgcn_sched_barrier(0);
    // ---- 14 gathers, asm-forced in flight together ----
    int4 ga[7], gb4[7];
    #pragma unroll
    for (int it = 0; it < 7; ++it) {
        int e8 = t + it * 256;
        int e8c = (e8 < 1600) ? e8 : 1599;
        int d8 = (e8c & 15) * 8;
        unsigned long long pa = (unsigned long long)(P1 + (size_t)idx[it].x * D + d8);
        unsigned long long pb = (unsigned long long)(P2 + (size_t)idx[it].y * D + d8);
        asm volatile("global_load_dwordx4 %0, %1, off" : "=&v"(ga[it])  : "v"(pa));
        asm volatile("global_load_dwordx4 %0, %1, off" : "=&v"(gb4[it]) : "v"(pb));
    }
    asm volatile("s_waitcnt vmcnt(0)" ::: "memory");
    __builtin_amdgcn_sched_barrier(0);
    // ---- convert (pair-unpack + fmax leaky + cvt_pk) -> bf16 LDS ----
    #pragma unroll
    for (int it = 0; it < 7; ++it) {
        int e8 = t + it * 256;
        if (e8 < 1600) {
            int m = e8 >> 4, d8 = (e8 & 15) * 8;
            int4 o;
            #pragma unroll
            for (int j = 0; j < 4; ++j) {
                unsigned int ua = ((const unsigned int*)&ga[it])[j];
                unsigned int ub = ((const unsigned int*)&gb4[it])[j];
                float lo = __uint_as_float(ua << 16) + __uint_as_float(ub << 16);
                float hi = __uint_as_float(ua & 0xFFFF0000u) + __uint_as_float(ub & 0xFFFF0000u);
                lo = fmaxf(lo, 0.01f * lo);            // leakyrelu, slope 0.01
                hi = fmaxf(hi, 0.01f * hi);
                unsigned int r;
                asm("v_cvt_pk_bf16_f32 %0, %1, %2" : "=v"(r) : "v"(lo), "v"(hi));
                ((unsigned int*)&o)[j] = r;
            }
            *(int4*)(proj + m * 136 + d8) = o;
        }
    }
    __syncthreads();   // proj + aw/gw visible
    // scores: tab = t>>7, half g = (t>>6)&1, m = t&63 (m<50 valid)
    {
        int tab = t >> 7, g = (t >> 6) & 1, m = t & 63;
        float s = 0.f;
        if (m < MM) {
            const unsigned short* pr = proj + (tab * MM + m) * 136 + g * 64;
            #pragma unroll
            for (int i = 0; i < 8; ++i) {
                short8 v8 = *(const short8*)(pr + i * 8);
                #pragma unroll
                for (int j = 0; j < 8; ++j)
                    s += bf2f((unsigned short)v8[j]) * aw[g * 64 + i * 8 + j];
            }
        }
        scp[tab][g][m] = s;
    }
    __syncthreads();
    // softmax per table: wave 0 -> tabA, wave 1 -> tabB
    if (t < 128) {
        int tab = t >> 6, m = t & 63;
        float v = (m < MM) ? (scp[tab][0][m] + scp[tab][1][m] + attn_b[0]) : -1e30f;
        float mx = v;
        #pragma unroll
        for (int o = 32; o > 0; o >>= 1) mx = fmaxf(mx, __shfl_xor(mx, o, 64));
        float ev = (m < MM) ? __expf(v - mx) : 0.f;
        float sm = ev;
        #pragma unroll
        for (int o = 32; o > 0; o >>= 1) sm += __shfl_xor(sm, o, 64);
        if (m < MM) scw[tab * 64 + m] = ev / sm;
    }
    __syncthreads();
    // agg: tab = t>>7, d = t&127
    int tab = t >> 7, d = t & 127;
    float agg = 0.f;
    #pragma unroll 5
    for (int m = 0; m < MM; ++m)
        agg += scw[tab * 64 + m] * bf2f(proj[(tab * MM + m) * 136 + d]);
    // gate scalar per table (2 waves each)
    float gpart = agg * gw[d];
    #pragma unroll
    for (int o = 32; o > 0; o >>= 1) gpart += __shfl_xor(gpart, o, 64);
    if ((t & 63) == 0) redg[t >> 6] = gpart;
    __syncthreads();
    if (t == 0)  gateS[0] = sigf(redg[0] + redg[1] + gate_lb[0] + gate_b[0]);
    if (t == 64) gateS[1] = sigf(redg[2] + redg[3] + gate_lb[0] + gate_b[0]);
    __syncthreads();
    float embd = emb[(size_t)selfid * D + d];
    float val = gateS[tab] * agg + (1.f - gateS[tab]) * embd;
    if (tab == 1) oth[d] = val;
    __syncthreads();
    if (tab == 0) {
        float r = 0.5f * (val + oth[d]);
        outp[d] = r;
        if (isq) qvbf[(size_t)item * DM + side * D + d] = f2bf(r);
    }
}

// ---------------------------------------------------------------------------
// Kernel 3 (round-17, replaces k_sg1/k_sg2/k_sg3/k_sgwhh): full sv -> sg ->
// sgW chain in ONE kernel, 32 blocks.  Each block REDUNDANTLY computes
// hid = relu(p1_W@s+b) (2 rows/thread) and h = p2_W@hid + b + s (1 row/
// thread) -- ~0.26M MAC + ~1MB L2 reads per block, a few us -- then LN
// in-register and its own 64-row sgW slice.  No inter-block dependency,
// no sync tricks.  Saves 3 launch boundaries.  (Summation order differs
// from the old split kernels -> tiny fp32 drift; absmax may wobble.)
// ---------------------------------------------------------------------------
__global__ __launch_bounds__(256) void k_sg(
    const float* __restrict__ sv, const float* __restrict__ p1_W,
    const float* __restrict__ p1_b, const float* __restrict__ p2_W,
    const float* __restrict__ p2_b, const float* __restrict__ ln_a,
    const float* __restrict__ ln_b, const float* __restrict__ Whh,
    float* __restrict__ sgb, float* __restrict__ sgW)
{
    __shared__ float s[DM];
    __shared__ float hid[2 * DM];
    __shared__ float red[8];
    int t = threadIdx.x;
    s[t] = sv[t];
    __syncthreads();
    // hid: rows t and t+256
    #pragma unroll
    for (int rr = 0; rr < 2; ++rr) {
        int j = t + rr * 256;
        const float* w = p1_W + (size_t)j * DM;
        float a = p1_b[j];
        #pragma unroll 8
        for (int i = 0; i < 64; ++i) {
            float4 v = *(const float4*)(w + i * 4);
            a += v.x * s[i * 4] + v.y * s[i * 4 + 1]
               + v.z * s[i * 4 + 2] + v.w * s[i * 4 + 3];
        }
        hid[j] = fmaxf(a, 0.f);
    }
    __syncthreads();
    // h: row t (kept in register)
    float x;
    {
        const float* w = p2_W + (size_t)t * (2 * DM);
        float a = p2_b[t] + s[t];
        #pragma unroll 8
        for (int i = 0; i < 128; ++i) {
            float4 v = *(const float4*)(w + i * 4);
            a += v.x * hid[i * 4] + v.y * hid[i * 4 + 1]
               + v.z * hid[i * 4 + 2] + v.w * hid[i * 4 + 3];
        }
        x = a;
    }
    // layernorm (ddof=1), in-register h
    float sm = x;
    #pragma unroll
    for (int o = 32; o > 0; o >>= 1) sm += __shfl_xor(sm, o, 64);
    if ((t & 63) == 0) red[t >> 6] = sm;
    __syncthreads();
    float mu = (red[0] + red[1] + red[2] + red[3]) * (1.0f / 256.0f);
    float dv = x - mu;
    float sq = dv * dv;
    #pragma unroll
    for (int o = 32; o > 0; o >>= 1) sq += __shfl_xor(sq, o, 64);
    if ((t & 63) == 0) red[4 + (t >> 6)] = sq;
    __syncthreads();
    float var = (red[4] + red[5] + red[6] + red[7]) * (1.0f / 255.0f);  // ddof=1
    float sig = sqrtf(var);
    float sgv = dv / (sig + 0.001f) * ln_a[t] + ln_b[t];
    s[t] = sgv;                         // safe: all p2 dots done (red barriers)
    if (blockIdx.x == 0) sgb[t] = sgv;
    __syncthreads();
    // sgW slice: k = blockIdx.x*64 + (t>>2), 4 lanes per row
    int k = blockIdx.x * 64 + (t >> 2);
    int pp = t & 3;
    const float* w = Whh + (size_t)k * HSZ + DM + pp * 64;
    float a = 0.f;
    #pragma unroll
    for (int i = 0; i < 16; ++i) {
        float4 v = *(const float4*)(w + i * 4);
        int c = pp * 64 + i * 4;
        a += v.x * s[c] + v.y * s[c + 1] + v.z * s[c + 2] + v.w * s[c + 3];
    }
    a += __shfl_xor(a, 1, 64);
    a += __shfl_xor(a, 2, 64);
    if (pp == 0) sgW[k] = a;
}

// ---------------------------------------------------------------------------
// Kernel 4: FULLY FUSED 4-step LSTM, dead-half trimmed (verified R6/R7/R11:
// absmax unchanged).  Block = 16 batch rows, 512 threads (8 waves), grid 256.
// Wave w owns H-col tiles {w, w+8} for ALL FOUR gates -> c-update fully
// in-wave.  hq passes between steps via an 8.4 KB LDS bf16 A-buffer.
// ---------------------------------------------------------------------------
__global__ __launch_bounds__(512, 2) void k_lstm_fused(
    const float* __restrict__ qv, const unsigned short* __restrict__ qvbf,
    const unsigned short* __restrict__ Wihp, const unsigned short* __restrict__ Whhp,
    const float* __restrict__ gb, const float* __restrict__ sgW,
    const float* __restrict__ sg, float* __restrict__ out)
{
    __shared__ unsigned short Ab[16 * 264];    // 8448 B, hq tile between steps
    __shared__ float redbuf[8][16];
    int t = threadIdx.x;
    int lane = t & 63, w = t >> 6;
    int nl = lane & 15, quad = lane >> 4;
    int b0 = blockIdx.x * 16;

    // fill A with qvbf rows (step-1 input); 512 threads x 1 int4 = 16x256
    {
        int row = t >> 5, c16 = t & 31;
        *(int4*)(Ab + row * 264 + c16 * 8) =
            *(const int4*)(qvbf + (size_t)(b0 + row) * DM + c16 * 8);
    }
    int kt[2] = { w, w + 8 };              // this wave's H-col tiles (<16)

    float sgWreg[2][4], qvreg[2][4], sgreg2[2];
    float cc[2][4];                        // c state, fp32
    ushort4 g0s[2][4];                     // g0 state, bf16 packed
    #pragma unroll
    for (int j = 0; j < 2; ++j) {
        #pragma unroll
        for (int g = 0; g < 4; ++g)
            sgWreg[j][g] = sgW[g * 512 + kt[j] * 16 + nl];
        sgreg2[j] = sg[kt[j] * 16 + nl];
        #pragma unroll
        for (int r = 0; r < 4; ++r)
            qvreg[j][r] = qv[(size_t)(b0 + quad * 4 + r) * DM + kt[j] * 16 + nl];
    }
    __syncthreads();

    // ---- steps 1..3 (write hq back to Ab) ----
    #pragma unroll 1
    for (int st = 0; st < 3; ++st) {
        short8 af[8];
        #pragma unroll
        for (int ks = 0; ks < 8; ++ks)
            af[ks] = *(const short8*)(Ab + nl * 264 + ks * 32 + quad * 8);
        const unsigned short* Bp = (st == 0) ? Wihp : Whhp;
        floatx4 acc[2][4];
        #pragma unroll
        for (int j = 0; j < 2; ++j)
            #pragma unroll
            for (int g = 0; g < 4; ++g)
                acc[j][g] = (floatx4){0.f, 0.f, 0.f, 0.f};
        #pragma unroll
        for (int j = 0; j < 2; ++j)
            #pragma unroll
            for (int g = 0; g < 4; ++g) {
                int T = g * 32 + kt[j];
                #pragma unroll
                for (int ks = 0; ks < 8; ++ks) {
                    short8 bfr = *(const short8*)(Bp + ((size_t)(T * 8 + ks) * 64 + lane) * 8);
                    acc[j][g] = __builtin_amdgcn_mfma_f32_16x16x32_bf16(
                        af[ks], bfr, acc[j][g], 0, 0, 0);
                }
            }
        float hval[2][4];
        if (st == 0) {
            #pragma unroll
            for (int j = 0; j < 2; ++j) {
                float bi  = gb[0 * 512 + kt[j] * 16 + nl];
                float bf_ = gb[1 * 512 + kt[j] * 16 + nl];
                float bg  = gb[2 * 512 + kt[j] * 16 + nl];
                float bo  = gb[3 * 512 + kt[j] * 16 + nl];
                #pragma unroll
                for (int r = 0; r < 4; ++r) {
                    float gi_ = acc[j][0][r] + bi;
                    float gf_ = acc[j][1][r] + bf_;
                    float gg_ = acc[j][2][r] + bg;
                    float go_ = acc[j][3][r] + bo;
                    ((unsigned short*)&g0s[j][0])[r] = f2bf(gi_);
                    ((unsigned short*)&g0s[j][1])[r] = f2bf(gf_);
                    ((unsigned short*)&g0s[j][2])[r] = f2bf(gg_);
                    ((unsigned short*)&g0s[j][3])[r] = f2bf(go_);
                    float cn = sigf(gi_) * tanhfast(gg_);
                    cc[j][r] = cn;
                    hval[j][r] = qvreg[j][r] + sigf(go_) * tanhfast(cn);
                }
            }
        } else {
            #pragma unroll
            for (int j = 0; j < 2; ++j)
                #pragma unroll
                for (int r = 0; r < 4; ++r) {
                    float gi_ = acc[j][0][r] + sgWreg[j][0] + bf2f(((unsigned short*)&g0s[j][0])[r]);
                    float gf_ = acc[j][1][r] + sgWreg[j][1] + bf2f(((unsigned short*)&g0s[j][1])[r]);
                    float gg_ = acc[j][2][r] + sgWreg[j][2] + bf2f(((unsigned short*)&g0s[j][2])[r]);
                    float go_ = acc[j][3][r] + sgWreg[j][3] + bf2f(((unsigned short*)&g0s[j][3])[r]);
                    float cn = sigf(gf_) * cc[j][r] + sigf(gi_) * tanhfast(gg_);
                    cc[j][r] = cn;
                    hval[j][r] = qvreg[j][r] + sigf(go_) * tanhfast(cn);
                }
        }
        __syncthreads();   // all waves done READING Ab
        #pragma unroll
        for (int j = 0; j < 2; ++j)
            #pragma unroll
            for (int r = 0; r < 4; ++r)
                Ab[(quad * 4 + r) * 264 + kt[j] * 16 + nl] = f2bf(hval[j][r]);
        __syncthreads();   // writes visible
    }

    // ---- step 4: dot(hq4, sg) into out ----
    {
        short8 af[8];
        #pragma unroll
        for (int ks = 0; ks < 8; ++ks)
            af[ks] = *(const short8*)(Ab + nl * 264 + ks * 32 + quad * 8);
        floatx4 acc[2][4];
        #pragma unroll
        for (int j = 0; j < 2; ++j)
            #pragma unroll
            for (int g = 0; g < 4; ++g)
                acc[j][g] = (floatx4){0.f, 0.f, 0.f, 0.f};
        #pragma unroll
        for (int j = 0; j < 2; ++j)
            #pragma unroll
            for (int g = 0; g < 4; ++g) {
                int T = g * 32 + kt[j];
                #pragma unroll
                for (int ks = 0; ks < 8; ++ks) {
                    short8 bfr = *(const short8*)(Whhp + ((size_t)(T * 8 + ks) * 64 + lane) * 8);
                    acc[j][g] = __builtin_amdgcn_mfma_f32_16x16x32_bf16(
                        af[ks], bfr, acc[j][g], 0, 0, 0);
                }
            }
        float part[4] = {0.f, 0.f, 0.f, 0.f};
        #pragma unroll
        for (int j = 0; j < 2; ++j)
            #pragma unroll
            for (int r = 0; r < 4; ++r) {
                float gi_ = acc[j][0][r] + sgWreg[j][0] + bf2f(((unsigned short*)&g0s[j][0])[r]);
                float gf_ = acc[j][1][r] + sgWreg[j][1] + bf2f(((unsigned short*)&g0s[j][1])[r]);
                float gg_ = acc[j][2][r] + sgWreg[j][2] + bf2f(((unsigned short*)&g0s[j][2])[r]);
                float go_ = acc[j][3][r] + sgWreg[j][3] + bf2f(((unsigned short*)&g0s[j][3])[r]);
                float cn = sigf(gf_) * cc[j][r] + sigf(gi_) * tanhfast(gg_);
                float h = qvreg[j][r] + sigf(go_) * tanhfast(cn);
                part[r] += h * sgreg2[j];
            }
        #pragma unroll
        for (int r = 0; r < 4; ++r) {
            float p = part[r];
            p += __shfl_xor(p, 1, 64);
            p += __shfl_xor(p, 2, 64);
            p += __shfl_xor(p, 4, 64);
            p += __shfl_xor(p, 8, 64);
            if (nl == 0) redbuf[w][quad * 4 + r] = p;
        }
    }
    __syncthreads();
    if (t < 16) {
        float s = 0.f;
        #pragma unroll
        for (int w2 = 0; w2 < 8; ++w2) s += redbuf[w2][t];
        out[b0 + t] = s;
    }
}

// ---------------------------------------------------------------------------
extern "C" void kernel_launch(void* const* d_in, const int* in_sizes, int n_in,
                              void* d_out, int out_size, void* d_ws, size_t ws_size,
                              hipStream_t stream) {
    const int* query   = (const int*)d_in[0];
    const int* support = (const int*)d_in[1];
    const int* q_l1 = (const int*)d_in[2];
    const int* q_l2 = (const int*)d_in[3];
    const int* q_r1 = (const int*)d_in[5];
    const int* q_r2 = (const int*)d_in[6];
    const int* s_l1 = (const int*)d_in[8];
    const int* s_l2 = (const int*)d_in[9];
    const int* s_r1 = (const int*)d_in[11];
    const int* s_r2 = (const int*)d_in[12];
    const float* emb    = (const float*)d_in[14];
    const float* gcn_W  = (const float*)d_in[15];
    const float* gcn_lb = (const float*)d_in[16];
    const float* gcn_b  = (const float*)d_in[17];
    const float* attn_W = (const float*)d_in[18];
    const float* attn_b = (const float*)d_in[19];
    const float* gate_W = (const float*)d_in[20];
    const float* gate_lb = (const float*)d_in[21];
    const float* gate_b  = (const float*)d_in[22];
    const float* p1_W = (const float*)d_in[23];
    const float* p1_b = (const float*)d_in[24];
    const float* p2_W = (const float*)d_in[25];
    const float* p2_b = (const float*)d_in[26];
    const float* ln_a = (const float*)d_in[27];
    const float* ln_b = (const float*)d_in[28];
    const float* Wih  = (const float*)d_in[29];
    const float* Whh  = (const float*)d_in[30];
    const float* bih  = (const float*)d_in[31];
    const float* bhh  = (const float*)d_in[32];

    // workspace layout: bf16 buffers first, then fp32 (16B-aligned blocks)
    unsigned short* P1   = (unsigned short*)d_ws;               // (V+1)*128
    unsigned short* P2   = P1 + (size_t)(VSZ + 1) * D;
    unsigned short* Wihp = P2 + (size_t)(VSZ + 1) * D;          // 65536*8
    unsigned short* Whhp = Wihp + (size_t)65536 * 8;            // 65536*8
    unsigned short* qvbf = Whhp + (size_t)65536 * 8;            // NB*256
    float* fws = (float*)(qvbf + (size_t)NB * DM);
    float* gbv = fws;  fws += G4;
    float* qvb = fws;  fws += (size_t)NB * DM;                  // 4 MB
    float* svb = fws;  fws += DM;
    float* sgb = fws;  fws += DM;
    float* sgW = fws;  fws += G4 + 4;   // keep next block 16B-aligned
    (void)in_sizes; (void)n_in; (void)out_size; (void)ws_size;

    // 4 launches (was 7): proj+pack, nbr, sg-chain, fused LSTM.
    k_proj_mfma<<<PROJ_BLKS + 520, 256, 0, stream>>>(
        emb, gcn_W, Wih, Whh, bih, bhh, gcn_lb, gcn_b,
        P1, P2, Wihp, Whhp, gbv, VSZ + 1);
    k_nbr<<<2 * (NB + 1), 256, 0, stream>>>(
        query, support, q_l1, q_l2, q_r1, q_r2, s_l1, s_l2, s_r1, s_r2,
        P1, P2, emb, attn_W, attn_b, gate_W, gate_lb, gate_b, qvb, qvbf, svb);
    k_sg<<<32, 256, 0, stream>>>(
        svb, p1_W, p1_b, p2_W, p2_b, ln_a, ln_b, Whh, sgb, sgW);
    k_lstm_fused<<<256, 512, 0, stream>>>(
        qvb, qvbf, Wihp, Whhp, gbv, sgW, sgb, (float*)d_out);
}

// Round 13
// 347.923 us; speedup vs baseline: 1.0933x; 1.0933x over previous
//
#include <hip/hip_runtime.h>

// Problem constants (match reference)
#define D    128      // embedding dim
#define VSZ  200000   // vocab (emb has VSZ+1 rows, last row = 0)
#define NB   4096     // batch B
#define MM   50       // neighbors
#define DM   256      // 2*D
#define HSZ  512      // H
#define G4   2048     // 4*H

typedef __attribute__((ext_vector_type(8))) short short8;   // 8 bf16 = 4 VGPRs
typedef __attribute__((ext_vector_type(4))) float floatx4;  // MFMA acc

__device__ __forceinline__ float sigf(float x) { return 1.0f / (1.0f + __expf(-x)); }
__device__ __forceinline__ float tanhfast(float x) { return 1.0f - 2.0f / (__expf(2.0f * x) + 1.0f); }
__device__ __forceinline__ unsigned short f2bf(float x) {
    unsigned int u = __float_as_uint(x);
    u += 0x7FFFu + ((u >> 16) & 1u);   // round-to-nearest-even
    return (unsigned short)(u >> 16);
}
__device__ __forceinline__ float bf2f(unsigned short s) {
    return __uint_as_float(((unsigned int)s) << 16);
}

// async 16B global->LDS DMA (gfx950).  lds dest must be wave-uniform;
// HW writes dest + lane*16.  size must be a literal (4/12/16).
__device__ __forceinline__ void async_copy16(void* lds, const void* gsrc) {
    __builtin_amdgcn_global_load_lds(
        (const __attribute__((address_space(1))) unsigned int*)gsrc,
        (__attribute__((address_space(3))) unsigned int*)lds, 16, 0, 0);
}

// ---------------------------------------------------------------------------
// Kernel 0 (merged): pack Wih (2048x256) and Whh[:, :256] into fragment-linear
// bf16 (chunk idx = (tile*8+ks)*64+lane), gb = bih+bhh, AND repack gcn_W
// (128x256 fp32) into bf16 Wb[n][k].  (R12's merge of this into k_proj
// REGRESSED +31us total -- launch gaps are small on the graph-captured
// harness; reverted to the R11-measured best.)
// ---------------------------------------------------------------------------
__global__ __launch_bounds__(256) void k_pack(
    const float* __restrict__ Wih, const float* __restrict__ Whh,
    const float* __restrict__ bih, const float* __restrict__ bhh,
    const float* __restrict__ gcn_W,
    unsigned short* __restrict__ Wihp, unsigned short* __restrict__ Whhp,
    float* __restrict__ gb, unsigned short* __restrict__ Wb)
{
    int idx = blockIdx.x * 256 + threadIdx.x;
    if (idx < 131072) {
        int ci = idx & 65535;
        int lane = ci & 63, rest = ci >> 6;
        int ks = rest & 7, tile = rest >> 3;
        int n = tile * 16 + (lane & 15), k = ks * 32 + (lane >> 4) * 8;
        const float* src = (idx < 65536) ? (Wih + (size_t)n * 256 + k)
                                         : (Whh + (size_t)n * 512 + k);
        unsigned short* dst = (idx < 65536) ? Wihp : Whhp;
        short8 o;
        #pragma unroll
        for (int j = 0; j < 8; ++j) o[j] = (short)f2bf(src[j]);
        *(short8*)(dst + (size_t)ci * 8) = o;
    } else if (idx < 131072 + 2048) {
        int i = idx - 131072;
        gb[i] = bih[i] + bhh[i];
    } else if (idx < 131072 + 2048 + 32768) {
        int i = idx - (131072 + 2048);
        int n = i >> 7, k = i & 127;
        float v = (n < 128) ? gcn_W[n * 256 + k] : gcn_W[(n - 128) * 256 + 128 + k];
        Wb[i] = f2bf(v);
    }
}

// ---------------------------------------------------------------------------
// Kernel 1: P = emb @ Wcat^T via bf16 MFMA.  Software-pipelined grid-stride
// loop (verified R7: k_proj off the top-5; duty-cycle theory confirmed).
// 768 blocks (3/CU), double-buffered 16KB LDS, counted vmcnt, lgkm-only
// second barrier, Wb fragments hoisted, byte^=(row&7)<<5 swizzle both sides.
// ---------------------------------------------------------------------------
__global__ __launch_bounds__(256, 3) void k_proj_mfma(
    const float* __restrict__ emb, const unsigned short* __restrict__ Wb,
    const float* __restrict__ gcn_lb, const float* __restrict__ gcn_b,
    unsigned short* __restrict__ P1, unsigned short* __restrict__ P2, int nrows)
{
    __shared__ __align__(16) unsigned char Buf[2][16384];   // fp32 A, swizzled
    __shared__ unsigned short C[32 * 264];                  // 16896 B
    int t = threadIdx.x;
    int lane = t & 63, w = t >> 6;
    int nl = lane & 15, quad = lane >> 4;
    int n0 = w * 64;
    int G = gridDim.x;
    int ntile = (nrows + 31) >> 5;

    auto STAGE = [&](int pb, int tile) {
        int v0 = tile * 32;
        #pragma unroll
        for (int it = 0; it < 4; ++it) {
            int chunk = w * 4 + it;                // 16 chunks of 1KB
            int o = chunk * 1024 + lane * 16;      // linear LDS byte
            int row = o >> 9;
            int b = o & 511;
            int bs = b ^ ((row & 7) << 5);         // inverse swizzle on source
            int v = v0 + row;
            v = (v < nrows) ? v : (nrows - 1);     // clamp tail (stores guarded)
            async_copy16(Buf[pb] + chunk * 1024,
                         (const char*)emb + (size_t)v * 512 + bs);
        }
    };

    // hoist Wb fragments once: L2-resident, reused for every tile
    short8 bfr[4][4];
    #pragma unroll
    for (int nt = 0; nt < 4; ++nt)
        #pragma unroll
        for (int ks = 0; ks < 4; ++ks)
            bfr[nt][ks] = *(const short8*)(Wb + (size_t)(n0 + nt * 16 + nl) * 128 + ks * 32 + quad * 8);

    STAGE(0, blockIdx.x);                          // prologue
    int pb = 0;
    bool first = true;
    for (int tile = blockIdx.x; tile < ntile; tile += G) {
        int nxt = tile + G;
        bool pf = (nxt < ntile);
        if (pf) STAGE(pb ^ 1, nxt);
        // counted wait: newest (4 prefetch [+4 stores after iter 0]) may stay
        // outstanding; everything older (current buffer's DMA) must be done.
        if (first) {
            if (pf) asm volatile("s_waitcnt vmcnt(4)" ::: "memory");
            else    asm volatile("s_waitcnt vmcnt(0)" ::: "memory");
        } else {
            if (pf) asm volatile("s_waitcnt vmcnt(8)" ::: "memory");
            else    asm volatile("s_waitcnt vmcnt(4)" ::: "memory");
        }
        __builtin_amdgcn_sched_barrier(0);
        __builtin_amdgcn_s_barrier();
        __builtin_amdgcn_sched_barrier(0);

        // ---- compute 32-row tile from Buf[pb] ----
        floatx4 acc[2][4];
        #pragma unroll
        for (int mt = 0; mt < 2; ++mt)
            #pragma unroll
            for (int nt = 0; nt < 4; ++nt)
                acc[mt][nt] = (floatx4){0.f, 0.f, 0.f, 0.f};
        const char* Sb = (const char*)Buf[pb];
        #pragma unroll
        for (int ks = 0; ks < 4; ++ks) {
            short8 af[2];
            #pragma unroll
            for (int mt = 0; mt < 2; ++mt) {
                int row = mt * 16 + nl;
                int b = ks * 128 + quad * 32;
                int ba = row * 512 + (b ^ ((row & 7) << 5));   // swizzled read
                float4 lo = *(const float4*)(Sb + ba);
                float4 hi = *(const float4*)(Sb + ba + 16);
                short8 a;
                a[0] = (short)f2bf(lo.x); a[1] = (short)f2bf(lo.y);
                a[2] = (short)f2bf(lo.z); a[3] = (short)f2bf(lo.w);
                a[4] = (short)f2bf(hi.x); a[5] = (short)f2bf(hi.y);
                a[6] = (short)f2bf(hi.z); a[7] = (short)f2bf(hi.w);
                af[mt] = a;
            }
            #pragma unroll
            for (int mt = 0; mt < 2; ++mt)
                #pragma unroll
                for (int nt = 0; nt < 4; ++nt)
                    acc[mt][nt] = __builtin_amdgcn_mfma_f32_16x16x32_bf16(
                        af[mt], bfr[nt][ks], acc[mt][nt], 0, 0, 0);
        }

        // ---- C-stage (bf16) ----
        #pragma unroll
        for (int nt = 0; nt < 4; ++nt) {
            int col = n0 + nt * 16 + nl;
            float bias = (col < 128) ? (gcn_lb[col] + gcn_b[col]) : 0.f;
            #pragma unroll
            for (int mt = 0; mt < 2; ++mt)
                #pragma unroll
                for (int reg = 0; reg < 4; ++reg)
                    C[(mt * 16 + quad * 4 + reg) * 264 + col] =
                        f2bf(acc[mt][nt][reg] + bias);
        }
        // lgkm-only barrier: C visible + Buf[pb] reads retired, WITHOUT
        // draining the in-flight prefetch (no vmcnt here).
        asm volatile("s_waitcnt lgkmcnt(0)" ::: "memory");
        __builtin_amdgcn_sched_barrier(0);
        __builtin_amdgcn_s_barrier();
        __builtin_amdgcn_sched_barrier(0);

        // ---- coalesced stores: 1024 16B chunks ----
        #pragma unroll
        for (int it = 0; it < 4; ++it) {
            int c = t + 256 * it;
            int row = c >> 5, c8 = c & 31;
            int v = tile * 32 + row;
            if (v < nrows) {
                int4 val = *(const int4*)(C + row * 264 + c8 * 8);
                unsigned short* dst = (c8 < 16) ? (P1 + (size_t)v * D + c8 * 8)
                                                : (P2 + (size_t)v * D + (c8 - 16) * 8);
                *(int4*)dst = val;
            }
        }
        pb ^= 1;
        first = false;
    }
}

// ---------------------------------------------------------------------------
// Kernel 2: neighbor aggregation.  ASM-forced gather pipeline (R11: 68us,
// identical to R9 -> random-gather service floor confirmed; frozen).
// ---------------------------------------------------------------------------
__global__ __launch_bounds__(256, 4) void k_nbr(
    const int* __restrict__ query, const int* __restrict__ support,
    const int* __restrict__ q_l1, const int* __restrict__ q_l2,
    const int* __restrict__ q_r1, const int* __restrict__ q_r2,
    const int* __restrict__ s_l1, const int* __restrict__ s_l2,
    const int* __restrict__ s_r1, const int* __restrict__ s_r2,
    const unsigned short* __restrict__ P1, const unsigned short* __restrict__ P2,
    const float* __restrict__ emb,
    const float* __restrict__ attn_W, const float* __restrict__ attn_b,
    const float* __restrict__ gate_W, const float* __restrict__ gate_lb,
    const float* __restrict__ gate_b,
    float* __restrict__ qv, unsigned short* __restrict__ qvbf,
    float* __restrict__ sv)
{
    __shared__ unsigned short proj[2 * MM * 136];   // bf16, 27.2 KB
    __shared__ float scw[2 * 64];
    __shared__ float scp[2][2][64];
    __shared__ float aw[D], gw[D];
    __shared__ float redg[4];
    __shared__ float gateS[2];
    __shared__ float oth[D];

    int bid = blockIdx.x;
    int item = bid >> 1;
    int side = bid & 1;
    int t = threadIdx.x;

    const int* cA; const int* cB; int selfid; float* outp; bool isq;
    if (item < NB) {
        isq = true;
        cA = (side ? q_r1 : q_l1) + (size_t)item * MM * 2;
        cB = (side ? q_r2 : q_l2) + (size_t)item * MM * 2;
        selfid = query[item * 2 + side];
        outp = qv + (size_t)item * DM + side * D;
    } else {
        isq = false;
        int i2 = item - NB;
        cA = (side ? s_r1 : s_l1) + (size_t)i2 * MM * 2;
        cB = (side ? s_r2 : s_l2) + (size_t)i2 * MM * 2;
        selfid = support[i2 * 2 + side];
        outp = sv + (size_t)i2 * DM + side * D;
    }
    if (t < D) { aw[t] = attn_W[t]; gw[t] = gate_W[t]; }

    // ---- 7 idx loads, asm-forced in flight together ----
    int2 idx[7];
    #pragma unroll
    for (int it = 0; it < 7; ++it) {
        int e8 = t + it * 256;
        int e8c = (e8 < 1600) ? e8 : 1599;
        int m = e8c >> 4;
        unsigned long long ca = (unsigned long long)
            ((m < MM) ? (cA + 2 * m) : (cB + 2 * (m - MM)));
        asm volatile("global_load_dwordx2 %0, %1, off"
                     : "=&v"(idx[it]) : "v"(ca));
    }
    asm volatile("s_waitcnt vmcnt(0)" ::: "memory");
    __builtin_amdgcn_sched_barrier(0);
    // ---- 14 gathers, asm-forced in flight together ----
    int4 ga[7], gb4[7];
    #pragma unroll
    for (int it = 0; it < 7; ++it) {
        int e8 = t + it * 256;
        int e8c = (e8 < 1600) ? e8 : 1599;
        int d8 = (e8c & 15) * 8;
        unsigned long long pa = (unsigned long long)(P1 + (size_t)idx[it].x * D + d8);
        unsigned long long pb = (unsigned long long)(P2 + (size_t)idx[it].y * D + d8);
        asm volatile("global_load_dwordx4 %0, %1, off" : "=&v"(ga[it])  : "v"(pa));
        asm volatile("global_load_dwordx4 %0, %1, off" : "=&v"(gb4[it]) : "v"(pb));
    }
    asm volatile("s_waitcnt vmcnt(0)" ::: "memory");
    __builtin_amdgcn_sched_barrier(0);
    // ---- convert (pair-unpack + fmax leaky + cvt_pk) -> bf16 LDS ----
    #pragma unroll
    for (int it = 0; it < 7; ++it) {
        int e8 = t + it * 256;
        if (e8 < 1600) {
            int m = e8 >> 4, d8 = (e8 & 15) * 8;
            int4 o;
            #pragma unroll
            for (int j = 0; j < 4; ++j) {
                unsigned int ua = ((const unsigned int*)&ga[it])[j];
                unsigned int ub = ((const unsigned int*)&gb4[it])[j];
                float lo = __uint_as_float(ua << 16) + __uint_as_float(ub << 16);
                float hi = __uint_as_float(ua & 0xFFFF0000u) + __uint_as_float(ub & 0xFFFF0000u);
                lo = fmaxf(lo, 0.01f * lo);            // leakyrelu, slope 0.01
                hi = fmaxf(hi, 0.01f * hi);
                unsigned int r;
                asm("v_cvt_pk_bf16_f32 %0, %1, %2" : "=v"(r) : "v"(lo), "v"(hi));
                ((unsigned int*)&o)[j] = r;
            }
            *(int4*)(proj + m * 136 + d8) = o;
        }
    }
    __syncthreads();   // proj + aw/gw visible
    // scores: tab = t>>7, half g = (t>>6)&1, m = t&63 (m<50 valid)
    {
        int tab = t >> 7, g = (t >> 6) & 1, m = t & 63;
        float s = 0.f;
        if (m < MM) {
            const unsigned short* pr = proj + (tab * MM + m) * 136 + g * 64;
            #pragma unroll
            for (int i = 0; i < 8; ++i) {
                short8 v8 = *(const short8*)(pr + i * 8);
                #pragma unroll
                for (int j = 0; j < 8; ++j)
                    s += bf2f((unsigned short)v8[j]) * aw[g * 64 + i * 8 + j];
            }
        }
        scp[tab][g][m] = s;
    }
    __syncthreads();
    // softmax per table: wave 0 -> tabA, wave 1 -> tabB
    if (t < 128) {
        int tab = t >> 6, m = t & 63;
        float v = (m < MM) ? (scp[tab][0][m] + scp[tab][1][m] + attn_b[0]) : -1e30f;
        float mx = v;
        #pragma unroll
        for (int o = 32; o > 0; o >>= 1) mx = fmaxf(mx, __shfl_xor(mx, o, 64));
        float ev = (m < MM) ? __expf(v - mx) : 0.f;
        float sm = ev;
        #pragma unroll
        for (int o = 32; o > 0; o >>= 1) sm += __shfl_xor(sm, o, 64);
        if (m < MM) scw[tab * 64 + m] = ev / sm;
    }
    __syncthreads();
    // agg: tab = t>>7, d = t&127
    int tab = t >> 7, d = t & 127;
    float agg = 0.f;
    #pragma unroll 5
    for (int m = 0; m < MM; ++m)
        agg += scw[tab * 64 + m] * bf2f(proj[(tab * MM + m) * 136 + d]);
    // gate scalar per table (2 waves each)
    float gpart = agg * gw[d];
    #pragma unroll
    for (int o = 32; o > 0; o >>= 1) gpart += __shfl_xor(gpart, o, 64);
    if ((t & 63) == 0) redg[t >> 6] = gpart;
    __syncthreads();
    if (t == 0)  gateS[0] = sigf(redg[0] + redg[1] + gate_lb[0] + gate_b[0]);
    if (t == 64) gateS[1] = sigf(redg[2] + redg[3] + gate_lb[0] + gate_b[0]);
    __syncthreads();
    float embd = emb[(size_t)selfid * D + d];
    float val = gateS[tab] * agg + (1.f - gateS[tab]) * embd;
    if (tab == 1) oth[d] = val;
    __syncthreads();
    if (tab == 0) {
        float r = 0.5f * (val + oth[d]);
        outp[d] = r;
        if (isq) qvbf[(size_t)item * DM + side * D + d] = f2bf(r);
    }
}

// ---------------------------------------------------------------------------
// Kernel 3 (split): support vector -> sg intermediates.
// ---------------------------------------------------------------------------
__global__ __launch_bounds__(256) void k_sg1(
    const float* __restrict__ sv, const float* __restrict__ p1_W,
    const float* __restrict__ p1_b, float* __restrict__ hid)
{
    __shared__ float s[DM];
    int t = threadIdx.x;
    s[t] = sv[t];
    __syncthreads();
    int j = blockIdx.x * 32 + (t >> 3);   // 16 blocks * 32 rows = 512
    int pp = t & 7;                       // 8 lanes per row, 32 cols each
    const float* w = p1_W + (size_t)j * DM + pp * 32;
    float a = 0.f;
    #pragma unroll
    for (int i = 0; i < 8; ++i) {
        float4 v = *(const float4*)(w + i * 4);
        int c = pp * 32 + i * 4;
        a += v.x * s[c] + v.y * s[c + 1] + v.z * s[c + 2] + v.w * s[c + 3];
    }
    a += __shfl_xor(a, 1, 64);
    a += __shfl_xor(a, 2, 64);
    a += __shfl_xor(a, 4, 64);
    if (pp == 0) hid[j] = fmaxf(a + p1_b[j], 0.f);
}

__global__ __launch_bounds__(256) void k_sg2(
    const float* __restrict__ sv, const float* __restrict__ hid,
    const float* __restrict__ p2_W, const float* __restrict__ p2_b,
    float* __restrict__ h)
{
    __shared__ float hs[2 * DM];
    int t = threadIdx.x;
    hs[t] = hid[t]; hs[t + 256] = hid[t + 256];
    __syncthreads();
    int r = blockIdx.x * 32 + (t >> 3);   // 8 blocks * 32 rows = 256
    int pp = t & 7;                       // 8 lanes per row, 64 cols each
    const float* w = p2_W + (size_t)r * (2 * DM) + pp * 64;
    float a = 0.f;
    #pragma unroll
    for (int i = 0; i < 16; ++i) {
        float4 v = *(const float4*)(w + i * 4);
        int c = pp * 64 + i * 4;
        a += v.x * hs[c] + v.y * hs[c + 1] + v.z * hs[c + 2] + v.w * hs[c + 3];
    }
    a += __shfl_xor(a, 1, 64);
    a += __shfl_xor(a, 2, 64);
    a += __shfl_xor(a, 4, 64);
    if (pp == 0) h[r] = a + p2_b[r] + sv[r];
}

// ---------------------------------------------------------------------------
// Kernel 4: layernorm (recomputed redundantly per block -- cheap) + sgW
// matvec.  Block 0 also writes sgb for k_lstm_fused.
// ---------------------------------------------------------------------------
__global__ __launch_bounds__(256) void k_sgwhh(
    const float* __restrict__ h, const float* __restrict__ ln_a,
    const float* __restrict__ ln_b, const float* __restrict__ Whh,
    float* __restrict__ sgb, float* __restrict__ sgW)
{
    __shared__ float s[DM];
    __shared__ float red[8];
    int t = threadIdx.x;
    float x = h[t];
    float sm = x;
    #pragma unroll
    for (int o = 32; o > 0; o >>= 1) sm += __shfl_xor(sm, o, 64);
    if ((t & 63) == 0) red[t >> 6] = sm;
    __syncthreads();
    float mu = (red[0] + red[1] + red[2] + red[3]) * (1.0f / 256.0f);
    float dv = x - mu;
    float sq = dv * dv;
    #pragma unroll
    for (int o = 32; o > 0; o >>= 1) sq += __shfl_xor(sq, o, 64);
    if ((t & 63) == 0) red[4 + (t >> 6)] = sq;
    __syncthreads();
    float var = (red[4] + red[5] + red[6] + red[7]) * (1.0f / 255.0f);  // ddof=1
    float sig = sqrtf(var);
    float sgv = dv / (sig + 0.001f) * ln_a[t] + ln_b[t];
    s[t] = sgv;
    if (blockIdx.x == 0) sgb[t] = sgv;
    __syncthreads();
    int k = blockIdx.x * 64 + (t >> 2);   // 32 blocks * 64 rows = 2048
    int pp = t & 3;                       // 4 lanes per row, 64 cols each
    const float* w = Whh + (size_t)k * HSZ + DM + pp * 64;
    float a = 0.f;
    #pragma unroll
    for (int i = 0; i < 16; ++i) {
        float4 v = *(const float4*)(w + i * 4);
        int c = pp * 64 + i * 4;
        a += v.x * s[c] + v.y * s[c + 1] + v.z * s[c + 2] + v.w * s[c + 3];
    }
    a += __shfl_xor(a, 1, 64);
    a += __shfl_xor(a, 2, 64);
    if (pp == 0) sgW[k] = a;
}

// ---------------------------------------------------------------------------
// Kernel 5: FULLY FUSED 4-step LSTM, dead-half trimmed (verified R6/R7/R11:
// absmax unchanged).  Block = 16 batch rows, 512 threads (8 waves), grid 256.
// Wave w owns H-col tiles {w, w+8} for ALL FOUR gates -> c-update fully
// in-wave.  hq passes between steps via an 8.4 KB LDS bf16 A-buffer.
// ---------------------------------------------------------------------------
__global__ __launch_bounds__(512, 2) void k_lstm_fused(
    const float* __restrict__ qv, const unsigned short* __restrict__ qvbf,
    const unsigned short* __restrict__ Wihp, const unsigned short* __restrict__ Whhp,
    const float* __restrict__ gb, const float* __restrict__ sgW,
    const float* __restrict__ sg, float* __restrict__ out)
{
    __shared__ unsigned short Ab[16 * 264];    // 8448 B, hq tile between steps
    __shared__ float redbuf[8][16];
    int t = threadIdx.x;
    int lane = t & 63, w = t >> 6;
    int nl = lane & 15, quad = lane >> 4;
    int b0 = blockIdx.x * 16;

    // fill A with qvbf rows (step-1 input); 512 threads x 1 int4 = 16x256
    {
        int row = t >> 5, c16 = t & 31;
        *(int4*)(Ab + row * 264 + c16 * 8) =
            *(const int4*)(qvbf + (size_t)(b0 + row) * DM + c16 * 8);
    }
    int kt[2] = { w, w + 8 };              // this wave's H-col tiles (<16)

    float sgWreg[2][4], qvreg[2][4], sgreg2[2];
    float cc[2][4];                        // c state, fp32
    ushort4 g0s[2][4];                     // g0 state, bf16 packed
    #pragma unroll
    for (int j = 0; j < 2; ++j) {
        #pragma unroll
        for (int g = 0; g < 4; ++g)
            sgWreg[j][g] = sgW[g * 512 + kt[j] * 16 + nl];
        sgreg2[j] = sg[kt[j] * 16 + nl];
        #pragma unroll
        for (int r = 0; r < 4; ++r)
            qvreg[j][r] = qv[(size_t)(b0 + quad * 4 + r) * DM + kt[j] * 16 + nl];
    }
    __syncthreads();

    // ---- steps 1..3 (write hq back to Ab) ----
    #pragma unroll 1
    for (int st = 0; st < 3; ++st) {
        short8 af[8];
        #pragma unroll
        for (int ks = 0; ks < 8; ++ks)
            af[ks] = *(const short8*)(Ab + nl * 264 + ks * 32 + quad * 8);
        const unsigned short* Bp = (st == 0) ? Wihp : Whhp;
        floatx4 acc[2][4];
        #pragma unroll
        for (int j = 0; j < 2; ++j)
            #pragma unroll
            for (int g = 0; g < 4; ++g)
                acc[j][g] = (floatx4){0.f, 0.f, 0.f, 0.f};
        #pragma unroll
        for (int j = 0; j < 2; ++j)
            #pragma unroll
            for (int g = 0; g < 4; ++g) {
                int T = g * 32 + kt[j];
                #pragma unroll
                for (int ks = 0; ks < 8; ++ks) {
                    short8 bfr = *(const short8*)(Bp + ((size_t)(T * 8 + ks) * 64 + lane) * 8);
                    acc[j][g] = __builtin_amdgcn_mfma_f32_16x16x32_bf16(
                        af[ks], bfr, acc[j][g], 0, 0, 0);
                }
            }
        float hval[2][4];
        if (st == 0) {
            #pragma unroll
            for (int j = 0; j < 2; ++j) {
                float bi  = gb[0 * 512 + kt[j] * 16 + nl];
                float bf_ = gb[1 * 512 + kt[j] * 16 + nl];
                float bg  = gb[2 * 512 + kt[j] * 16 + nl];
                float bo  = gb[3 * 512 + kt[j] * 16 + nl];
                #pragma unroll
                for (int r = 0; r < 4; ++r) {
                    float gi_ = acc[j][0][r] + bi;
                    float gf_ = acc[j][1][r] + bf_;
                    float gg_ = acc[j][2][r] + bg;
                    float go_ = acc[j][3][r] + bo;
                    ((unsigned short*)&g0s[j][0])[r] = f2bf(gi_);
                    ((unsigned short*)&g0s[j][1])[r] = f2bf(gf_);
                    ((unsigned short*)&g0s[j][2])[r] = f2bf(gg_);
                    ((unsigned short*)&g0s[j][3])[r] = f2bf(go_);
                    float cn = sigf(gi_) * tanhfast(gg_);
                    cc[j][r] = cn;
                    hval[j][r] = qvreg[j][r] + sigf(go_) * tanhfast(cn);
                }
            }
        } else {
            #pragma unroll
            for (int j = 0; j < 2; ++j)
                #pragma unroll
                for (int r = 0; r < 4; ++r) {
                    float gi_ = acc[j][0][r] + sgWreg[j][0] + bf2f(((unsigned short*)&g0s[j][0])[r]);
                    float gf_ = acc[j][1][r] + sgWreg[j][1] + bf2f(((unsigned short*)&g0s[j][1])[r]);
                    float gg_ = acc[j][2][r] + sgWreg[j][2] + bf2f(((unsigned short*)&g0s[j][2])[r]);
                    float go_ = acc[j][3][r] + sgWreg[j][3] + bf2f(((unsigned short*)&g0s[j][3])[r]);
                    float cn = sigf(gf_) * cc[j][r] + sigf(gi_) * tanhfast(gg_);
                    cc[j][r] = cn;
                    hval[j][r] = qvreg[j][r] + sigf(go_) * tanhfast(cn);
                }
        }
        __syncthreads();   // all waves done READING Ab
        #pragma unroll
        for (int j = 0; j < 2; ++j)
            #pragma unroll
            for (int r = 0; r < 4; ++r)
                Ab[(quad * 4 + r) * 264 + kt[j] * 16 + nl] = f2bf(hval[j][r]);
        __syncthreads();   // writes visible
    }

    // ---- step 4: dot(hq4, sg) into out ----
    {
        short8 af[8];
        #pragma unroll
        for (int ks = 0; ks < 8; ++ks)
            af[ks] = *(const short8*)(Ab + nl * 264 + ks * 32 + quad * 8);
        floatx4 acc[2][4];
        #pragma unroll
        for (int j = 0; j < 2; ++j)
            #pragma unroll
            for (int g = 0; g < 4; ++g)
                acc[j][g] = (floatx4){0.f, 0.f, 0.f, 0.f};
        #pragma unroll
        for (int j = 0; j < 2; ++j)
            #pragma unroll
            for (int g = 0; g < 4; ++g) {
                int T = g * 32 + kt[j];
                #pragma unroll
                for (int ks = 0; ks < 8; ++ks) {
                    short8 bfr = *(const short8*)(Whhp + ((size_t)(T * 8 + ks) * 64 + lane) * 8);
                    acc[j][g] = __builtin_amdgcn_mfma_f32_16x16x32_bf16(
                        af[ks], bfr, acc[j][g], 0, 0, 0);
                }
            }
        float part[4] = {0.f, 0.f, 0.f, 0.f};
        #pragma unroll
        for (int j = 0; j < 2; ++j)
            #pragma unroll
            for (int r = 0; r < 4; ++r) {
                float gi_ = acc[j][0][r] + sgWreg[j][0] + bf2f(((unsigned short*)&g0s[j][0])[r]);
                float gf_ = acc[j][1][r] + sgWreg[j][1] + bf2f(((unsigned short*)&g0s[j][1])[r]);
                float gg_ = acc[j][2][r] + sgWreg[j][2] + bf2f(((unsigned short*)&g0s[j][2])[r]);
                float go_ = acc[j][3][r] + sgWreg[j][3] + bf2f(((unsigned short*)&g0s[j][3])[r]);
                float cn = sigf(gf_) * cc[j][r] + sigf(gi_) * tanhfast(gg_);
                float h = qvreg[j][r] + sigf(go_) * tanhfast(cn);
                part[r] += h * sgreg2[j];
            }
        #pragma unroll
        for (int r = 0; r < 4; ++r) {
            float p = part[r];
            p += __shfl_xor(p, 1, 64);
            p += __shfl_xor(p, 2, 64);
            p += __shfl_xor(p, 4, 64);
            p += __shfl_xor(p, 8, 64);
            if (nl == 0) redbuf[w][quad * 4 + r] = p;
        }
    }
    __syncthreads();
    if (t < 16) {
        float s = 0.f;
        #pragma unroll
        for (int w2 = 0; w2 < 8; ++w2) s += redbuf[w2][t];
        out[b0 + t] = s;
    }
}

// ---------------------------------------------------------------------------
extern "C" void kernel_launch(void* const* d_in, const int* in_sizes, int n_in,
                              void* d_out, int out_size, void* d_ws, size_t ws_size,
                              hipStream_t stream) {
    const int* query   = (const int*)d_in[0];
    const int* support = (const int*)d_in[1];
    const int* q_l1 = (const int*)d_in[2];
    const int* q_l2 = (const int*)d_in[3];
    const int* q_r1 = (const int*)d_in[5];
    const int* q_r2 = (const int*)d_in[6];
    const int* s_l1 = (const int*)d_in[8];
    const int* s_l2 = (const int*)d_in[9];
    const int* s_r1 = (const int*)d_in[11];
    const int* s_r2 = (const int*)d_in[12];
    const float* emb    = (const float*)d_in[14];
    const float* gcn_W  = (const float*)d_in[15];
    const float* gcn_lb = (const float*)d_in[16];
    const float* gcn_b  = (const float*)d_in[17];
    const float* attn_W = (const float*)d_in[18];
    const float* attn_b = (const float*)d_in[19];
    const float* gate_W = (const float*)d_in[20];
    const float* gate_lb = (const float*)d_in[21];
    const float* gate_b  = (const float*)d_in[22];
    const float* p1_W = (const float*)d_in[23];
    const float* p1_b = (const float*)d_in[24];
    const float* p2_W = (const float*)d_in[25];
    const float* p2_b = (const float*)d_in[26];
    const float* ln_a = (const float*)d_in[27];
    const float* ln_b = (const float*)d_in[28];
    const float* Wih  = (const float*)d_in[29];
    const float* Whh  = (const float*)d_in[30];
    const float* bih  = (const float*)d_in[31];
    const float* bhh  = (const float*)d_in[32];

    // workspace layout: bf16 buffers first, then fp32 (16B-aligned blocks)
    unsigned short* P1   = (unsigned short*)d_ws;               // (V+1)*128
    unsigned short* P2   = P1 + (size_t)(VSZ + 1) * D;
    unsigned short* Wb   = P2 + (size_t)(VSZ + 1) * D;          // 256*128
    unsigned short* Wihp = Wb + 256 * 128;                      // 65536*8
    unsigned short* Whhp = Wihp + (size_t)65536 * 8;            // 65536*8
    unsigned short* qvbf = Whhp + (size_t)65536 * 8;            // NB*256
    float* fws = (float*)(qvbf + (size_t)NB * DM);
    float* gbv = fws;  fws += G4;
    float* qvb = fws;  fws += (size_t)NB * DM;                  // 4 MB
    float* svb = fws;  fws += DM;
    float* sgb = fws;  fws += DM;
    float* sgW = fws;  fws += G4 + 4;   // keep next block 16B-aligned
    float* hidb = fws; fws += 2 * DM;   // 512
    float* hb  = fws;  fws += DM;       // 256
    (void)in_sizes; (void)n_in; (void)out_size; (void)ws_size;

    k_pack<<<648, 256, 0, stream>>>(
        Wih, Whh, bih, bhh, gcn_W, Wihp, Whhp, gbv, Wb);
    k_proj_mfma<<<768, 256, 0, stream>>>(
        emb, Wb, gcn_lb, gcn_b, P1, P2, VSZ + 1);
    k_nbr<<<2 * (NB + 1), 256, 0, stream>>>(
        query, support, q_l1, q_l2, q_r1, q_r2, s_l1, s_l2, s_r1, s_r2,
        P1, P2, emb, attn_W, attn_b, gate_W, gate_lb, gate_b, qvb, qvbf, svb);
    k_sg1<<<16, 256, 0, stream>>>(svb, p1_W, p1_b, hidb);
    k_sg2<<<8, 256, 0, stream>>>(svb, hidb, p2_W, p2_b, hb);
    k_sgwhh<<<32, 256, 0, stream>>>(hb, ln_a, ln_b, Whh, sgb, sgW);
    k_lstm_fused<<<256, 512, 0, stream>>>(
        qvb, qvbf, Wihp, Whhp, gbv, sgW, sgb, (float*)d_out);
}